// Round 9
// baseline (95.123 us; speedup 1.0000x reference)
//
#include <hip/hip_runtime.h>

// GridSamplePScan: out[b,t,c] = sum_{k<=t} bilinear(images[b,k,c], wrap(base + cum_t - cum_k))
// B=4, L=32, C=16, H=W=64, fp32 in/out.
//
// R8: de-phase the pipes. R7 counters: iter = 5850 cy = VALU(3400) + LDS(2500)
//   -> pipes SERIALIZED by barrier phase-lock (one 1024-thr block/CU).
//   Fix: 2 independent 512-thr blocks per CU, each with its own 64KB single
//   LDS buffer (sync -> STAGE(i) -> sync -> compute(i), pure __syncthreads
//   semantics). Sibling blocks drift out of phase: one block's barrier/DMA
//   drain/ds_read burst overlaps the other's FMA phase -> max() not sum().
//   px math bit-identical to R7 (passed, absmax 0.0625).

constexpr int BN = 4, LN = 32, CN = 16, HWn = 4096;
constexpr int FRAME = CN * HWn;
constexpr size_t TIMG_BYTES = (size_t)BN * LN * HWn * CN * 2;  // 16 MB fp16
constexpr size_t CUM_BYTES  = (size_t)BN * LN * HWn * 2 * 4;   // 4 MB f32

// ---------------------------------------------------------------------------
// images fp32 [B,L,C,H,W] -> fp16 [B*L][chhalf(2)][4096 px][8ch] (16B cells)
// ---------------------------------------------------------------------------
__global__ __launch_bounds__(256) void prep_timg(
        const float* __restrict__ img, float4* __restrict__ timg) {
    const int bi = blockIdx.x, tile = bi & 15, f = bi >> 4;   // f = b*L + l
    const int p = (tile << 8) + threadIdx.x;
    const float* src = img + (size_t)f * FRAME + p;
#pragma unroll
    for (int g = 0; g < 2; ++g) {
        union { float4 f4; _Float16 h[8]; } cell;
#pragma unroll
        for (int j = 0; j < 8; ++j)
            cell.h[j] = (_Float16)src[(g * 8 + j) * HWn];     // coalesced
        timg[((size_t)f * 2 + g) * HWn + p] = cell.f4;        // 16B/lane
    }
}

// ---------------------------------------------------------------------------
__global__ __launch_bounds__(256) void prep_cum(
        const float* __restrict__ flows, float2* __restrict__ cum) {
    const int b = blockIdx.x >> 4;
    const int p = ((blockIdx.x & 15) << 8) + threadIdx.x;
    const float* fl = flows + (size_t)b * (LN * 2 * HWn) + p;
    float cx = 0.f, cy = 0.f;
    for (int l = 0; l < LN; ++l) {              // ascending == jnp.cumsum
        cx += fl[(2 * l) * HWn];
        cy += fl[(2 * l + 1) * HWn];
        cum[(size_t)(b * LN + l) * HWn + p] = make_float2(cx, cy);
    }
}

// ---------------------------------------------------------------------------
// Bilinear sample of one pixel from the LDS-resident 8-channel frame.
// Math bit-identical to the reference (and the passing R2/R7 kernels).
// ---------------------------------------------------------------------------
__device__ __forceinline__ void px_step(const float4* __restrict__ fr,
                                        float2 ct, float2 ck,
                                        float bx, float by,
                                        float* __restrict__ acc) {
    float vx = (bx + (ct.x - ck.x)) + 1.0f;     // (base + rel) + 1, ref order
    float vy = (by + (ct.y - ck.y)) + 1.0f;
    float mx = vx - 2.0f * floorf(vx * 0.5f);   // == jnp.mod(v,2) bitwise
    float my = vy - 2.0f * floorf(vy * 0.5f);
    // ((mx-1)+1) == mx bitwise (Sterbenz: mx-1 exact on [0,2), +1 re-exact),
    // so fold the ref's -1/+1 round-trip: ix = mx*32 - 0.5 (mul exact).
    float ix = mx * 32.0f - 0.5f;               // [-0.5, 63.5)
    float iy = my * 32.0f - 0.5f;
    float xf = floorf(ix), yf = floorf(iy);
    int x0 = (int)xf, y0 = (int)yf;             // [-1, 63]
    float wx1 = ix - xf, wy1 = iy - yf;
    float wx0 = 1.0f - wx1, wy0 = 1.0f - wy1;
    wx0 = (x0 >= 0) ? wx0 : 0.0f;               // zero-pad outside image
    wx1 = (x0 <= 62) ? wx1 : 0.0f;
    wy0 = (y0 >= 0) ? wy0 : 0.0f;
    wy1 = (y0 <= 62) ? wy1 : 0.0f;
    const int x0c = max(x0, 0), y0c = max(y0, 0);
    const int x1c = min(x0 + 1, 63), y1c = min(y0 + 1, 63);
    const float w00 = wx0 * wy0, w10 = wx1 * wy0;
    const float w01 = wx0 * wy1, w11 = wx1 * wy1;
    union { float4 f4; _Float16 h[8]; } g00, g10, g01, g11;
    const int r0 = (y0c << 6), r1 = (y1c << 6);
    g00.f4 = fr[r0 + x0c];                      // ds_read_b128
    g10.f4 = fr[r0 + x1c];
    g01.f4 = fr[r1 + x0c];
    g11.f4 = fr[r1 + x1c];
#pragma unroll
    for (int c = 0; c < 8; ++c)                 // v_fma_mix_f32: f32 accum
        acc[c] += ((w00 * (float)g00.h[c] + w10 * (float)g10.h[c])
                   + w01 * (float)g01.h[c]) + w11 * (float)g11.h[c];
}

// ---------------------------------------------------------------------------
// 512 blocks x 512 threads; 2 blocks/CU (64KB LDS each) for pipe de-phasing.
// Block = (b, pxq quarter, t-pair, chh). Each thread: 2 px, 8 ch, 2 t-phases.
// ---------------------------------------------------------------------------
__global__ __launch_bounds__(512, 4) void gsps_lds(
        const float2* __restrict__ cum,
        const char* __restrict__ timg,
        float* __restrict__ out) {
    extern __shared__ char smem[];              // 64 KB single buffer
    const int bid = blockIdx.x;                 // 512 blocks
    // bid&7 = XCD slot: (b, pxq-lowbit) -> b pinned to an XCD pair
    const int pxq  = ((bid & 1) << 1) | ((bid >> 3) & 1);
    const int b    = (bid >> 1) & 3;
    const int pair = (bid >> 4) & 15;
    const int chh  = bid >> 8;
    const int tid  = threadIdx.x;
    const int t1 = 31 - pair;                   // heavy phase t
    const int t2 = pair;                        // light phase t

    const int px0 = (pxq << 10) + tid;
    const int px1 = px0 + 512;
    const float bx0 = ((float)(px0 & 63) + 0.5f) * 0.03125f - 1.0f;
    const float by0 = ((float)(px0 >> 6) + 0.5f) * 0.03125f - 1.0f;
    const float bx1 = ((float)(px1 & 63) + 0.5f) * 0.03125f - 1.0f;
    const float by1 = ((float)(px1 >> 6) + 0.5f) * 0.03125f - 1.0f;

    const float2* cb = cum + (size_t)b * (LN * HWn);
    // frame k, channel-half chh byte offset: ((b*32+k)*2 + chh) * 65536
    const size_t chunk0 = (((size_t)b * LN * 2) + chh) << 16;
    const unsigned wbase = (unsigned)(tid & ~63) << 4;   // wave-uniform *1024

    // wave-uniform LDS base + lane*16 (HW rule); identity mapping to global
#define STAGE(KK) do {                                                        \
    const char* gsrc = timg + chunk0 + ((size_t)(KK) << 17);                  \
    _Pragma("unroll")                                                         \
    for (int j = 0; j < 8; ++j) {                                             \
        __builtin_amdgcn_global_load_lds(                                     \
            (const __attribute__((address_space(1))) void*)                  \
                (gsrc + j * 8192 + tid * 16),                                 \
            (__attribute__((address_space(3))) void*)                        \
                (smem + wbase + j * 8192),                                    \
            16, 0, 0);                                                        \
    }                                                                         \
} while (0)

    float acc0[8] = {0}, acc1[8] = {0};
    float2 ct0 = make_float2(0.f, 0.f), ct1 = ct0;
    float2 ckp0 = cb[px0], ckp1 = cb[px1];      // ck prefetch for iter 0 (k=0)

    for (int i = 0; i < 33; ++i) {
        const bool ph2 = (i > t1);
        const int k = ph2 ? (i - t1 - 1) : i;
        const int t = ph2 ? t2 : t1;

        __syncthreads();                        // (A) reads of frame i-1 done
        STAGE(i == 0 ? 0 : k);                  // DMA frame k -> sbuf
        __syncthreads();                        // (B) vmcnt(0) drained: ready
        // exposed drain ~300-500cy is covered by the sibling block on the CU

        const float2 ck0 = ckp0, ck1 = ckp1;
        if (i < 32) {                           // prefetch next ck pair
            const int kn = (i + 1 > t1) ? (i - t1) : (i + 1);
            ckp0 = cb[kn * HWn + px0];
            ckp1 = cb[kn * HWn + px1];
        }
        if (k == 0) {                           // phase start
            ct0 = cb[t * HWn + px0];
            ct1 = cb[t * HWn + px1];
#pragma unroll
            for (int c = 0; c < 8; ++c) { acc0[c] = 0.f; acc1[c] = 0.f; }
        }
        const float4* fr = (const float4*)smem;
        px_step(fr, ct0, ck0, bx0, by0, acc0);
        px_step(fr, ct1, ck1, bx1, by1, acc1);

        if (k == t) {                           // phase end: write out
            float* op = out + ((size_t)(b * LN + t) * CN + chh * 8) * HWn;
#pragma unroll
            for (int c = 0; c < 8; ++c) {
                op[c * HWn + px0] = acc0[c];
                op[c * HWn + px1] = acc1[c];
            }
        }
    }
#undef STAGE
}

// ---------------------------------------------------------------------------
// Fallback (ws too small / attr fails): direct fp32 gather (proven R1 kernel).
// ---------------------------------------------------------------------------
__global__ __launch_bounds__(256) void gsps_slow(
        const float* __restrict__ flows,
        const float* __restrict__ img,
        float* __restrict__ out) {
    const int bi = blockIdx.x;
    const int tile = bi & 15;
    const int rest = bi >> 4;
    const int t = 31 - (rest & 31);
    const int b = rest >> 5;
    const int p = (tile << 8) + threadIdx.x;
    const int h = p >> 6, w = p & 63;
    const float base_x = ((float)w + 0.5f) * 0.03125f - 1.0f;
    const float base_y = ((float)h + 0.5f) * 0.03125f - 1.0f;
    const float* fl = flows + (size_t)b * (LN * 2 * HWn) + p;

    float ctx = 0.f, cty = 0.f;
    for (int j = 0; j <= t; ++j) { ctx += fl[(2*j)*HWn]; cty += fl[(2*j+1)*HWn]; }

    float acc[16];
#pragma unroll
    for (int c = 0; c < 16; ++c) acc[c] = 0.f;

    float ckx = 0.f, cky = 0.f;
    for (int k = 0; k <= t; ++k) {
        ckx += fl[(2*k)*HWn]; cky += fl[(2*k+1)*HWn];
        float vx = (base_x + (ctx - ckx)) + 1.0f;
        float vy = (base_y + (cty - cky)) + 1.0f;
        float mx = vx - 2.0f * floorf(vx * 0.5f);
        float my = vy - 2.0f * floorf(vy * 0.5f);
        const float ix = ((mx - 1.0f) + 1.0f) * 32.0f - 0.5f;
        const float iy = ((my - 1.0f) + 1.0f) * 32.0f - 0.5f;
        const float x0f = floorf(ix), y0f = floorf(iy);
        const int x0 = (int)x0f, y0 = (int)y0f;
        const float wx1 = ix - x0f, wy1 = iy - y0f;
        const float wx0 = 1.0f - wx1, wy0 = 1.0f - wy1;
        const int x1 = x0 + 1, y1 = y0 + 1;
        const float fx0 = (x0 >= 0) ? 1.0f : 0.0f;
        const float fx1 = (x1 <= 63) ? 1.0f : 0.0f;
        const float fy0 = (y0 >= 0) ? 1.0f : 0.0f;
        const float fy1 = (y1 <= 63) ? 1.0f : 0.0f;
        const int x0c = (x0 < 0) ? 0 : x0, x1c = (x1 > 63) ? 63 : x1;
        const int y0c = (y0 < 0) ? 0 : y0, y1c = (y1 > 63) ? 63 : y1;
        const float w00 = (wx0*wy0)*(fx0*fy0), w10 = (wx1*wy0)*(fx1*fy0);
        const float w01 = (wx0*wy1)*(fx0*fy1), w11 = (wx1*wy1)*(fx1*fy1);
        const float* frm = img + (size_t)(b * LN + k) * FRAME;
        const int i00 = (y0c<<6)+x0c, i10 = (y0c<<6)+x1c;
        const int i01 = (y1c<<6)+x0c, i11 = (y1c<<6)+x1c;
#pragma unroll
        for (int c = 0; c < 16; ++c) {
            const float* pl = frm + c * HWn;
            acc[c] += ((w00*pl[i00] + w10*pl[i10]) + w01*pl[i01]) + w11*pl[i11];
        }
    }
    float* op = out + (size_t)(b * LN + t) * FRAME + p;
#pragma unroll
    for (int c = 0; c < 16; ++c) op[c * HWn] = acc[c];
}

extern "C" void kernel_launch(void* const* d_in, const int* in_sizes, int n_in,
                              void* d_out, int out_size, void* d_ws, size_t ws_size,
                              hipStream_t stream) {
    const float* flows  = (const float*)d_in[0];   // [4,32,2,64,64] f32
    const float* images = (const float*)d_in[1];   // [4,32,16,64,64] f32
    float* out = (float*)d_out;                    // [4,32,16,64,64] f32

    bool fast = (ws_size >= TIMG_BYTES + CUM_BYTES);
    if (fast) {
        hipError_t e = hipFuncSetAttribute(
            reinterpret_cast<const void*>(&gsps_lds),
            hipFuncAttributeMaxDynamicSharedMemorySize, 65536);
        if (e != hipSuccess) fast = false;
    }
    if (fast) {
        float4* timg = (float4*)d_ws;
        float2* cumw = (float2*)((char*)d_ws + TIMG_BYTES);
        prep_timg<<<BN * LN * 16, 256, 0, stream>>>(images, timg);
        prep_cum<<<BN * 16, 256, 0, stream>>>(flows, cumw);
        gsps_lds<<<512, 512, 65536, stream>>>(cumw, (const char*)timg, out);
    } else {
        gsps_slow<<<BN * LN * 16, 256, 0, stream>>>(flows, images, out);
    }
}

// Round 10
// 91.439 us; speedup vs baseline: 1.0403x; 1.0403x over previous
//
#include <hip/hip_runtime.h>

// GridSamplePScan: out[b,t,c] = sum_{k<=t} bilinear(images[b,k,c], wrap(base + cum_t - cum_k))
// B=4, L=32, C=16, H=W=64, fp32 in/out.
//
// R9: R7's proven schedule (STAGE issue after barrier, drain at NEXT barrier
//   -> DMA hidden under compute) + VALU diet:
//   - zero-padded 66x66 LDS frames: border cells are zeros -> no boundary
//     masks/clamps (reference zero-padding falls out of the data)
//   - fmaf MAC chain -> v_fma_mix_f32
//   - fract-based wrap (bitwise-equal to mod chain; exactness proof in code)
//   R8 lesson: sync->STAGE->sync exposes the drain; never do that.

constexpr int BN = 4, LN = 32, CN = 16, HWn = 4096;
constexpr int FRAME = CN * HWn;
constexpr int PW = 66, PCELLS = PW * PW;                       // 4356 cells
constexpr int CHUNK_B = PCELLS * 16;                           // 69696 B
constexpr size_t TIMG_BYTES = (size_t)BN * LN * 2 * CHUNK_B;   // ~17.8 MB
constexpr size_t CUM_BYTES  = (size_t)BN * LN * HWn * 2 * 4;   // 4 MB

// ---------------------------------------------------------------------------
// images fp32 [B,L,C,H,W] -> fp16 padded [B*L][chh(2)][66][66][8ch] 16B cells.
// Cell (y,x): interior (1..64)^2 = image px (y-1,x-1); border = zeros.
// ---------------------------------------------------------------------------
__global__ __launch_bounds__(1024) void prep_pad(
        const float* __restrict__ img, float4* __restrict__ timg) {
    const int f = blockIdx.x >> 1, g = blockIdx.x & 1;         // frame, chhalf
    const float* src = img + (size_t)f * FRAME + g * (8 * HWn);
    float4* dst = timg + (size_t)blockIdx.x * PCELLS;
    for (int q = threadIdx.x; q < PCELLS; q += 1024) {
        const int y = q / PW, x = q - y * PW;
        union { float4 f4; _Float16 h[8]; } cell;
        if (y >= 1 && y <= 64 && x >= 1 && x <= 64) {
            const int p = ((y - 1) << 6) + (x - 1);
#pragma unroll
            for (int c = 0; c < 8; ++c)
                cell.h[c] = (_Float16)src[c * HWn + p];        // coalesced
        } else {
            cell.f4 = make_float4(0.f, 0.f, 0.f, 0.f);         // zero pad
        }
        dst[q] = cell.f4;
    }
}

// ---------------------------------------------------------------------------
__global__ __launch_bounds__(256) void prep_cum(
        const float* __restrict__ flows, float2* __restrict__ cum) {
    const int b = blockIdx.x >> 4;
    const int p = ((blockIdx.x & 15) << 8) + threadIdx.x;
    const float* fl = flows + (size_t)b * (LN * 2 * HWn) + p;
    float cx = 0.f, cy = 0.f;
    for (int l = 0; l < LN; ++l) {              // ascending == jnp.cumsum
        cx += fl[(2 * l) * HWn];
        cy += fl[(2 * l + 1) * HWn];
        cum[(size_t)(b * LN + l) * HWn + p] = make_float2(cx, cy);
    }
}

// ---------------------------------------------------------------------------
// Bilinear from padded LDS frame. No masks/clamps: pad cells are zero.
// Wrap math: vx>=? any sign; u=vx*0.5 exact; fu=u-floor(u)=mod(vx,2)/2 exact;
// ixp = fu*64+0.5 = mod(vx,2)*32+0.5 = ref ix + 1; x0p=floor(ixp) in [0,64].
// ---------------------------------------------------------------------------
__device__ __forceinline__ void px_step(const float4* __restrict__ fr,
                                        float2 ct, float2 ck,
                                        float bx, float by,
                                        float* __restrict__ acc) {
    const float vx = (bx + (ct.x - ck.x)) + 1.0f;   // ref add order
    const float vy = (by + (ct.y - ck.y)) + 1.0f;
    const float ux = vx * 0.5f, uy = vy * 0.5f;
    const float fx = ux - floorf(ux);               // [0,1)
    const float fy = uy - floorf(uy);
    const float ixp = fmaf(fx, 64.0f, 0.5f);        // [0.5, 64.5)
    const float iyp = fmaf(fy, 64.0f, 0.5f);
    const float xf = floorf(ixp), yf = floorf(iyp);
    const int x0p = (int)xf, y0p = (int)yf;         // [0, 64]
    const float wx1 = ixp - xf, wy1 = iyp - yf;
    const float wx0 = 1.0f - wx1, wy0 = 1.0f - wy1;
    const float w00 = wx0 * wy0, w10 = wx1 * wy0;
    const float w01 = wx0 * wy1, w11 = wx1 * wy1;
    const int i00 = y0p * PW + x0p;                 // one mad; +1/+66/+67 fold
    union { float4 f4; _Float16 h[8]; } g00, g10, g01, g11;
    g00.f4 = fr[i00];                               // ds_read_b128 offset:0
    g10.f4 = fr[i00 + 1];                           // offset:16
    g01.f4 = fr[i00 + PW];                          // offset:1056
    g11.f4 = fr[i00 + PW + 1];                      // offset:1072
#pragma unroll
    for (int c = 0; c < 8; ++c) {                   // v_fma_mix_f32 chain
        float s = fmaf((float)g00.h[c], w00, acc[c]);
        s = fmaf((float)g10.h[c], w10, s);
        s = fmaf((float)g01.h[c], w01, s);
        acc[c] = fmaf((float)g11.h[c], w11, s);
    }
}

// ---------------------------------------------------------------------------
// 256 blocks x 1024 thr (1/CU). Block = (b, pxhalf, pair, chh); thread: 2 px,
// 8 ch, 2 t-phases (triangle-paired: 33 uniform k-iters).
// ---------------------------------------------------------------------------
__global__ __launch_bounds__(1024, 4) void gsps_lds(
        const float2* __restrict__ cum,
        const char* __restrict__ timg,
        float* __restrict__ out) {
    extern __shared__ char smem[];              // 2 x 69696 B double buffer
    const int bid = blockIdx.x;                 // 256 blocks
    const int xs  = bid & 7;                    // XCD slot
    const int b   = xs >> 1;                    // batch pinned to XCD pair
    const int pxh = xs & 1;
    const int seq = bid >> 3;
    const int pair = seq & 15;
    const int chh  = seq >> 4;
    const int tid  = threadIdx.x;
    const int t1 = 31 - pair;                   // heavy phase t
    const int t2 = pair;                        // light phase t

    const int px0 = (pxh << 11) + tid;
    const int px1 = px0 + 1024;
    const float bx0 = ((float)(px0 & 63) + 0.5f) * 0.03125f - 1.0f;
    const float by0 = ((float)(px0 >> 6) + 0.5f) * 0.03125f - 1.0f;
    const float bx1 = ((float)(px1 & 63) + 0.5f) * 0.03125f - 1.0f;
    const float by1 = ((float)(px1 >> 6) + 0.5f) * 0.03125f - 1.0f;

    const float2* cb = cum + (size_t)b * (LN * HWn);
    // chunk base for (b, k, chh): ((b*32 + k)*2 + chh) * CHUNK_B
    const size_t chunk0 = ((size_t)b * LN * 2 + chh) * CHUNK_B;
    const unsigned wbase = (unsigned)(tid & ~63) << 4;   // wave-uniform

    // LDS dest: wave-uniform base (+ HW lane*16); global src per-lane.
#define STAGE(KK, BUF) do {                                                   \
    const char* gsrc = timg + chunk0 + (size_t)(KK) * (2 * CHUNK_B);          \
    char* lbase = smem + (BUF) * CHUNK_B + wbase;                             \
    _Pragma("unroll")                                                         \
    for (int j = 0; j < 4; ++j) {                                             \
        __builtin_amdgcn_global_load_lds(                                     \
            (const __attribute__((address_space(1))) void*)                  \
                (gsrc + (j * 16384 + tid * 16)),                              \
            (__attribute__((address_space(3))) void*)(lbase + j * 16384),    \
            16, 0, 0);                                                        \
    }                                                                         \
    if (tid < PCELLS - 4096) {  /* tail cells 4096..4355 */                   \
        __builtin_amdgcn_global_load_lds(                                     \
            (const __attribute__((address_space(1))) void*)                  \
                (gsrc + (65536 + tid * 16)),                                  \
            (__attribute__((address_space(3))) void*)(lbase + 65536),        \
            16, 0, 0);                                                        \
    }                                                                         \
} while (0)

    float acc0[8] = {0}, acc1[8] = {0};
    float2 ct0 = make_float2(0.f, 0.f), ct1 = ct0;
    float2 ckp0 = cb[px0], ckp1 = cb[px1];      // ck prefetch for iter 0

    STAGE(0, 0);                                // prologue: frame 0 -> buf0

    for (int i = 0; i < 33; ++i) {
        const bool ph2 = (i > t1);
        const int k = ph2 ? (i - t1 - 1) : i;
        const int t = ph2 ? t2 : t1;

        // barrier drains vmcnt(0): STAGE(i) complete; buf^1 readers done
        __syncthreads();
        if (i < 32) {                           // issue next DMA now; it
            const int kn = (i + 1 > t1) ? (i - t1) : (i + 1);
            STAGE(kn, (i + 1) & 1);             // drains at NEXT barrier
        }

        const float2 ck0 = ckp0, ck1 = ckp1;
        if (i < 32) {                           // prefetch next ck pair
            const int kn = (i + 1 > t1) ? (i - t1) : (i + 1);
            ckp0 = cb[kn * HWn + px0];
            ckp1 = cb[kn * HWn + px1];
        }
        if (k == 0) {                           // phase start
            ct0 = cb[t * HWn + px0];
            ct1 = cb[t * HWn + px1];
#pragma unroll
            for (int c = 0; c < 8; ++c) { acc0[c] = 0.f; acc1[c] = 0.f; }
        }
        const float4* fr = (const float4*)(smem + (i & 1) * CHUNK_B);
        px_step(fr, ct0, ck0, bx0, by0, acc0);
        px_step(fr, ct1, ck1, bx1, by1, acc1);

        if (k == t) {                           // phase end: write out
            float* op = out + ((size_t)(b * LN + t) * CN + chh * 8) * HWn;
#pragma unroll
            for (int c = 0; c < 8; ++c) {
                op[c * HWn + px0] = acc0[c];
                op[c * HWn + px1] = acc1[c];
            }
        }
    }
#undef STAGE
}

// ---------------------------------------------------------------------------
// Fallback (ws too small / attr fails): direct fp32 gather (proven R1 kernel).
// ---------------------------------------------------------------------------
__global__ __launch_bounds__(256) void gsps_slow(
        const float* __restrict__ flows,
        const float* __restrict__ img,
        float* __restrict__ out) {
    const int bi = blockIdx.x;
    const int tile = bi & 15;
    const int rest = bi >> 4;
    const int t = 31 - (rest & 31);
    const int b = rest >> 5;
    const int p = (tile << 8) + threadIdx.x;
    const int h = p >> 6, w = p & 63;
    const float base_x = ((float)w + 0.5f) * 0.03125f - 1.0f;
    const float base_y = ((float)h + 0.5f) * 0.03125f - 1.0f;
    const float* fl = flows + (size_t)b * (LN * 2 * HWn) + p;

    float ctx = 0.f, cty = 0.f;
    for (int j = 0; j <= t; ++j) { ctx += fl[(2*j)*HWn]; cty += fl[(2*j+1)*HWn]; }

    float acc[16];
#pragma unroll
    for (int c = 0; c < 16; ++c) acc[c] = 0.f;

    float ckx = 0.f, cky = 0.f;
    for (int k = 0; k <= t; ++k) {
        ckx += fl[(2*k)*HWn]; cky += fl[(2*k+1)*HWn];
        float vx = (base_x + (ctx - ckx)) + 1.0f;
        float vy = (base_y + (cty - cky)) + 1.0f;
        float mx = vx - 2.0f * floorf(vx * 0.5f);
        float my = vy - 2.0f * floorf(vy * 0.5f);
        const float ix = ((mx - 1.0f) + 1.0f) * 32.0f - 0.5f;
        const float iy = ((my - 1.0f) + 1.0f) * 32.0f - 0.5f;
        const float x0f = floorf(ix), y0f = floorf(iy);
        const int x0 = (int)x0f, y0 = (int)y0f;
        const float wx1 = ix - x0f, wy1 = iy - y0f;
        const float wx0 = 1.0f - wx1, wy0 = 1.0f - wy1;
        const int x1 = x0 + 1, y1 = y0 + 1;
        const float fx0 = (x0 >= 0) ? 1.0f : 0.0f;
        const float fx1 = (x1 <= 63) ? 1.0f : 0.0f;
        const float fy0 = (y0 >= 0) ? 1.0f : 0.0f;
        const float fy1 = (y1 <= 63) ? 1.0f : 0.0f;
        const int x0c = (x0 < 0) ? 0 : x0, x1c = (x1 > 63) ? 63 : x1;
        const int y0c = (y0 < 0) ? 0 : y0, y1c = (y1 > 63) ? 63 : y1;
        const float w00 = (wx0*wy0)*(fx0*fy0), w10 = (wx1*wy0)*(fx1*fy0);
        const float w01 = (wx0*wy1)*(fx0*fy1), w11 = (wx1*wy1)*(fx1*fy1);
        const float* frm = img + (size_t)(b * LN + k) * FRAME;
        const int i00 = (y0c<<6)+x0c, i10 = (y0c<<6)+x1c;
        const int i01 = (y1c<<6)+x0c, i11 = (y1c<<6)+x1c;
#pragma unroll
        for (int c = 0; c < 16; ++c) {
            const float* pl = frm + c * HWn;
            acc[c] += ((w00*pl[i00] + w10*pl[i10]) + w01*pl[i01]) + w11*pl[i11];
        }
    }
    float* op = out + (size_t)(b * LN + t) * FRAME + p;
#pragma unroll
    for (int c = 0; c < 16; ++c) op[c * HWn] = acc[c];
}

extern "C" void kernel_launch(void* const* d_in, const int* in_sizes, int n_in,
                              void* d_out, int out_size, void* d_ws, size_t ws_size,
                              hipStream_t stream) {
    const float* flows  = (const float*)d_in[0];   // [4,32,2,64,64] f32
    const float* images = (const float*)d_in[1];   // [4,32,16,64,64] f32
    float* out = (float*)d_out;                    // [4,32,16,64,64] f32

    bool fast = (ws_size >= TIMG_BYTES + CUM_BYTES);
    if (fast) {
        hipError_t e = hipFuncSetAttribute(
            reinterpret_cast<const void*>(&gsps_lds),
            hipFuncAttributeMaxDynamicSharedMemorySize, 2 * CHUNK_B);
        if (e != hipSuccess) fast = false;
    }
    if (fast) {
        float4* timg = (float4*)d_ws;
        float2* cumw = (float2*)((char*)d_ws + TIMG_BYTES);
        prep_pad<<<BN * LN * 2, 1024, 0, stream>>>(images, timg);
        prep_cum<<<BN * 16, 256, 0, stream>>>(flows, cumw);
        gsps_lds<<<256, 1024, 2 * CHUNK_B, stream>>>(
            cumw, (const char*)timg, out);
    } else {
        gsps_slow<<<BN * LN * 16, 256, 0, stream>>>(flows, images, out);
    }
}

// Round 11
// 88.641 us; speedup vs baseline: 1.0731x; 1.0316x over previous
//
#include <hip/hip_runtime.h>

// GridSamplePScan: out[b,t,c] = sum_{k<=t} bilinear(images[b,k,c], wrap(base + cum_t - cum_k))
// B=4, L=32, C=16, H=W=64, fp32 in/out.
//
// R10: clean de-phase test. R9 iter = VALU(2580) + LDS(~2800) SUMMED (barrier
//   phase-lock of the single block/CU). Fix: 2 independent 512-thr blocks/CU
//   with IDENTICAL total per-CU work+traffic (R8's confounds removed):
//   cell = 4ch x fp16 = 8B, chunk = 66*66*8 = 34848B, dbuf 69696B/block,
//   2 blocks/CU = 139KB LDS. Block=(b,pxh,pair,chq): 512 blocks x 512 thr,
//   4 px/thread x 4ch. Same R7/R9 schedule: barrier -> issue STAGE(next) ->
//   compute(cur); DMA drains at NEXT barrier (hidden under compute).

constexpr int BN = 4, LN = 32, CN = 16, HWn = 4096;
constexpr int FRAME = CN * HWn;
constexpr int PW = 66, PCELLS = PW * PW;                       // 4356 cells
constexpr int CH_B = PCELLS * 8;                               // 34848 B
constexpr size_t TIMG_BYTES = (size_t)BN * LN * 4 * CH_B;      // ~17.8 MB
constexpr size_t CUM_BYTES  = (size_t)BN * LN * HWn * 2 * 4;   // 4 MB

// ---------------------------------------------------------------------------
// images fp32 [B,L,C,H,W] -> fp16 padded [B*L][chq(4)][66*66][4ch] 8B cells.
// Cell (y,x): interior (1..64)^2 = image px (y-1,x-1); border = zeros.
// ---------------------------------------------------------------------------
__global__ __launch_bounds__(512) void prep_pad(
        const float* __restrict__ img, uint2* __restrict__ timg) {
    const int f = blockIdx.x >> 2, q4 = blockIdx.x & 3;        // frame, chq
    const float* src = img + (size_t)f * FRAME + q4 * (4 * HWn);
    uint2* dst = timg + (size_t)blockIdx.x * PCELLS;
    for (int q = threadIdx.x; q < PCELLS; q += 512) {
        const int y = q / PW, x = q - y * PW;                  // magic-mul div
        union { uint2 u2; _Float16 h[4]; } cell;
        if (y >= 1 && y <= 64 && x >= 1 && x <= 64) {
            const int p = ((y - 1) << 6) + (x - 1);
#pragma unroll
            for (int c = 0; c < 4; ++c)
                cell.h[c] = (_Float16)src[c * HWn + p];        // coalesced
        } else {
            cell.u2 = make_uint2(0u, 0u);                      // zero pad
        }
        dst[q] = cell.u2;
    }
}

// ---------------------------------------------------------------------------
__global__ __launch_bounds__(256) void prep_cum(
        const float* __restrict__ flows, float2* __restrict__ cum) {
    const int b = blockIdx.x >> 4;
    const int p = ((blockIdx.x & 15) << 8) + threadIdx.x;
    const float* fl = flows + (size_t)b * (LN * 2 * HWn) + p;
    float cx = 0.f, cy = 0.f;
    for (int l = 0; l < LN; ++l) {              // ascending == jnp.cumsum
        cx += fl[(2 * l) * HWn];
        cy += fl[(2 * l + 1) * HWn];
        cum[(size_t)(b * LN + l) * HWn + p] = make_float2(cx, cy);
    }
}

// ---------------------------------------------------------------------------
// Bilinear from padded LDS frame (4ch cells). No masks: pad cells are zero.
// Wrap: u=vx*0.5 exact; fu=u-floor(u)=mod(vx,2)/2 exact; ixp=fu*64+0.5 =
// ref ix + 1 bitwise; x0p=floor(ixp) in [0,64]. Proven R9 (absmax 0.0625).
// ---------------------------------------------------------------------------
__device__ __forceinline__ void px_step4(const uint2* __restrict__ fr,
                                         float2 ct, float2 ck,
                                         float bx, float by,
                                         float* __restrict__ acc) {
    const float vx = (bx + (ct.x - ck.x)) + 1.0f;   // ref add order
    const float vy = (by + (ct.y - ck.y)) + 1.0f;
    const float ux = vx * 0.5f, uy = vy * 0.5f;
    const float fx = ux - floorf(ux);               // [0,1)
    const float fy = uy - floorf(uy);
    const float ixp = fmaf(fx, 64.0f, 0.5f);        // [0.5, 64.5)
    const float iyp = fmaf(fy, 64.0f, 0.5f);
    const float xf = floorf(ixp), yf = floorf(iyp);
    const int x0p = (int)xf, y0p = (int)yf;         // [0, 64]
    const float wx1 = ixp - xf, wy1 = iyp - yf;
    const float wx0 = 1.0f - wx1, wy0 = 1.0f - wy1;
    const float w00 = wx0 * wy0, w10 = wx1 * wy0;
    const float w01 = wx0 * wy1, w11 = wx1 * wy1;
    const int i00 = y0p * PW + x0p;
    union { uint2 u2; _Float16 h[4]; } g00, g10, g01, g11;
    g00.u2 = fr[i00];                               // ds_read_b64
    g10.u2 = fr[i00 + 1];
    g01.u2 = fr[i00 + PW];
    g11.u2 = fr[i00 + PW + 1];
#pragma unroll
    for (int c = 0; c < 4; ++c) {                   // v_fma_mix chain
        float s = fmaf((float)g00.h[c], w00, acc[c]);
        s = fmaf((float)g10.h[c], w10, s);
        s = fmaf((float)g01.h[c], w01, s);
        acc[c] = fmaf((float)g11.h[c], w11, s);
    }
}

// ---------------------------------------------------------------------------
// 512 blocks x 512 thr (2 independent blocks/CU). Block = (b, pxh, pair, chq);
// thread: 4 px, 4 ch, 2 t-phases (triangle-paired: 33 uniform k-iters).
// ---------------------------------------------------------------------------
__global__ __launch_bounds__(512, 4) void gsps_lds(
        const float2* __restrict__ cum,
        const char* __restrict__ timg,
        float* __restrict__ out) {
    extern __shared__ char smem[];              // 2 x 34848 B double buffer
    const int bid = blockIdx.x;                 // 512 blocks
    const int b    = bid & 3;                   // XCD slot low bits: b, chq
    const int chq  = (bid >> 2) & 3;
    const int pair = (bid >> 4) & 15;
    const int pxh  = bid >> 8;                  // high bit: pxh-siblings share
    const int tid  = threadIdx.x;               //   chunk on same XCD
    const int t1 = 31 - pair;                   // heavy phase t
    const int t2 = pair;                        // light phase t

    // 4 pixels per thread: px_j = pxh*2048 + j*512 + tid
    const int px_0 = (pxh << 11) + tid;
    const float bxA = ((float)(px_0 & 63) + 0.5f) * 0.03125f - 1.0f;
    const float byA = ((float)(px_0 >> 6) + 0.5f) * 0.03125f - 1.0f;
    const float bxB = ((float)((px_0 + 512) & 63) + 0.5f) * 0.03125f - 1.0f;
    const float byB = ((float)((px_0 + 512) >> 6) + 0.5f) * 0.03125f - 1.0f;
    const float bxC = ((float)((px_0 + 1024) & 63) + 0.5f) * 0.03125f - 1.0f;
    const float byC = ((float)((px_0 + 1024) >> 6) + 0.5f) * 0.03125f - 1.0f;
    const float bxD = ((float)((px_0 + 1536) & 63) + 0.5f) * 0.03125f - 1.0f;
    const float byD = ((float)((px_0 + 1536) >> 6) + 0.5f) * 0.03125f - 1.0f;

    const float2* cb = cum + (size_t)b * (LN * HWn) + px_0;  // +j*512+k*HWn
    // chunk for (b,k,chq): ((b*32+k)*4 + chq) * CH_B
    const size_t chunk0 = ((size_t)b * LN * 4 + chq) * CH_B;
    const unsigned wbase = (unsigned)(tid & ~63) << 4;   // wave-uniform

    // LDS dest: wave-uniform base (+ HW lane*16); identity map to global.
#define STAGE(KK, BUF) do {                                                   \
    const char* gsrc = timg + chunk0 + (size_t)(KK) * (4 * CH_B);             \
    char* lbase = smem + (BUF) * CH_B + wbase;                                \
    _Pragma("unroll")                                                         \
    for (int j = 0; j < 4; ++j) {                                             \
        __builtin_amdgcn_global_load_lds(                                     \
            (const __attribute__((address_space(1))) void*)                  \
                (gsrc + (j * 8192 + tid * 16)),                               \
            (__attribute__((address_space(3))) void*)(lbase + j * 8192),     \
            16, 0, 0);                                                        \
    }                                                                         \
    if (tid < (CH_B - 32768) / 16) {  /* tail: 130 thr x 16B */               \
        __builtin_amdgcn_global_load_lds(                                     \
            (const __attribute__((address_space(1))) void*)                  \
                (gsrc + (32768 + tid * 16)),                                  \
            (__attribute__((address_space(3))) void*)(lbase + 32768),        \
            16, 0, 0);                                                        \
    }                                                                         \
} while (0)

    float accA[4] = {0}, accB[4] = {0}, accC[4] = {0}, accD[4] = {0};
    float2 ctA = make_float2(0.f, 0.f), ctB = ctA, ctC = ctA, ctD = ctA;
    float2 ckpA = cb[0], ckpB = cb[512], ckpC = cb[1024], ckpD = cb[1536];

    STAGE(0, 0);                                // prologue: frame 0 -> buf0

    for (int i = 0; i < 33; ++i) {
        const bool ph2 = (i > t1);
        const int k = ph2 ? (i - t1 - 1) : i;
        const int t = ph2 ? t2 : t1;

        // barrier drains vmcnt(0): STAGE(i) complete; buf^1 readers done
        __syncthreads();
        if (i < 32) {                           // issue next DMA; it drains
            const int kn = (i + 1 > t1) ? (i - t1) : (i + 1);
            STAGE(kn, (i + 1) & 1);             // at the NEXT barrier
        }

        const float2 ckA = ckpA, ckB = ckpB, ckC = ckpC, ckD = ckpD;
        if (i < 32) {                           // prefetch next ck quads
            const int kn = (i + 1 > t1) ? (i - t1) : (i + 1);
            const float2* cn = cb + kn * HWn;
            ckpA = cn[0]; ckpB = cn[512]; ckpC = cn[1024]; ckpD = cn[1536];
        }
        if (k == 0) {                           // phase start
            const float2* cl = cb + t * HWn;
            ctA = cl[0]; ctB = cl[512]; ctC = cl[1024]; ctD = cl[1536];
#pragma unroll
            for (int c = 0; c < 4; ++c)
                { accA[c] = 0.f; accB[c] = 0.f; accC[c] = 0.f; accD[c] = 0.f; }
        }
        const uint2* fr = (const uint2*)(smem + (i & 1) * CH_B);
        px_step4(fr, ctA, ckA, bxA, byA, accA);
        px_step4(fr, ctB, ckB, bxB, byB, accB);
        px_step4(fr, ctC, ckC, bxC, byC, accC);
        px_step4(fr, ctD, ckD, bxD, byD, accD);

        if (k == t) {                           // phase end: write out
            float* op = out + ((size_t)(b * LN + t) * CN + chq * 4) * HWn
                      + px_0;
#pragma unroll
            for (int c = 0; c < 4; ++c) {
                op[c * HWn         ] = accA[c];
                op[c * HWn + 512   ] = accB[c];
                op[c * HWn + 1024  ] = accC[c];
                op[c * HWn + 1536  ] = accD[c];
            }
        }
    }
#undef STAGE
}

// ---------------------------------------------------------------------------
// Fallback (ws too small / attr fails): direct fp32 gather (proven R1 kernel).
// ---------------------------------------------------------------------------
__global__ __launch_bounds__(256) void gsps_slow(
        const float* __restrict__ flows,
        const float* __restrict__ img,
        float* __restrict__ out) {
    const int bi = blockIdx.x;
    const int tile = bi & 15;
    const int rest = bi >> 4;
    const int t = 31 - (rest & 31);
    const int b = rest >> 5;
    const int p = (tile << 8) + threadIdx.x;
    const int h = p >> 6, w = p & 63;
    const float base_x = ((float)w + 0.5f) * 0.03125f - 1.0f;
    const float base_y = ((float)h + 0.5f) * 0.03125f - 1.0f;
    const float* fl = flows + (size_t)b * (LN * 2 * HWn) + p;

    float ctx = 0.f, cty = 0.f;
    for (int j = 0; j <= t; ++j) { ctx += fl[(2*j)*HWn]; cty += fl[(2*j+1)*HWn]; }

    float acc[16];
#pragma unroll
    for (int c = 0; c < 16; ++c) acc[c] = 0.f;

    float ckx = 0.f, cky = 0.f;
    for (int k = 0; k <= t; ++k) {
        ckx += fl[(2*k)*HWn]; cky += fl[(2*k+1)*HWn];
        float vx = (base_x + (ctx - ckx)) + 1.0f;
        float vy = (base_y + (cty - cky)) + 1.0f;
        float mx = vx - 2.0f * floorf(vx * 0.5f);
        float my = vy - 2.0f * floorf(vy * 0.5f);
        const float ix = ((mx - 1.0f) + 1.0f) * 32.0f - 0.5f;
        const float iy = ((my - 1.0f) + 1.0f) * 32.0f - 0.5f;
        const float x0f = floorf(ix), y0f = floorf(iy);
        const int x0 = (int)x0f, y0 = (int)y0f;
        const float wx1 = ix - x0f, wy1 = iy - y0f;
        const float wx0 = 1.0f - wx1, wy0 = 1.0f - wy1;
        const int x1 = x0 + 1, y1 = y0 + 1;
        const float fx0 = (x0 >= 0) ? 1.0f : 0.0f;
        const float fx1 = (x1 <= 63) ? 1.0f : 0.0f;
        const float fy0 = (y0 >= 0) ? 1.0f : 0.0f;
        const float fy1 = (y1 <= 63) ? 1.0f : 0.0f;
        const int x0c = (x0 < 0) ? 0 : x0, x1c = (x1 > 63) ? 63 : x1;
        const int y0c = (y0 < 0) ? 0 : y0, y1c = (y1 > 63) ? 63 : y1;
        const float w00 = (wx0*wy0)*(fx0*fy0), w10 = (wx1*wy0)*(fx1*fy0);
        const float w01 = (wx0*wy1)*(fx0*fy1), w11 = (wx1*wy1)*(fx1*fy1);
        const float* frm = img + (size_t)(b * LN + k) * FRAME;
        const int i00 = (y0c<<6)+x0c, i10 = (y0c<<6)+x1c;
        const int i01 = (y1c<<6)+x0c, i11 = (y1c<<6)+x1c;
#pragma unroll
        for (int c = 0; c < 16; ++c) {
            const float* pl = frm + c * HWn;
            acc[c] += ((w00*pl[i00] + w10*pl[i10]) + w01*pl[i01]) + w11*pl[i11];
        }
    }
    float* op = out + (size_t)(b * LN + t) * FRAME + p;
#pragma unroll
    for (int c = 0; c < 16; ++c) op[c * HWn] = acc[c];
}

extern "C" void kernel_launch(void* const* d_in, const int* in_sizes, int n_in,
                              void* d_out, int out_size, void* d_ws, size_t ws_size,
                              hipStream_t stream) {
    const float* flows  = (const float*)d_in[0];   // [4,32,2,64,64] f32
    const float* images = (const float*)d_in[1];   // [4,32,16,64,64] f32
    float* out = (float*)d_out;                    // [4,32,16,64,64] f32

    bool fast = (ws_size >= TIMG_BYTES + CUM_BYTES);
    if (fast) {
        hipError_t e = hipFuncSetAttribute(
            reinterpret_cast<const void*>(&gsps_lds),
            hipFuncAttributeMaxDynamicSharedMemorySize, 2 * CH_B);
        if (e != hipSuccess) fast = false;
    }
    if (fast) {
        uint2* timg = (uint2*)d_ws;
        float2* cumw = (float2*)((char*)d_ws + TIMG_BYTES);
        prep_pad<<<BN * LN * 4, 512, 0, stream>>>(images, timg);
        prep_cum<<<BN * 16, 256, 0, stream>>>(flows, cumw);
        gsps_lds<<<512, 512, 2 * CH_B, stream>>>(
            cumw, (const char*)timg, out);
    } else {
        gsps_slow<<<BN * LN * 16, 256, 0, stream>>>(flows, images, out);
    }
}

// Round 13
// 84.784 us; speedup vs baseline: 1.1220x; 1.0455x over previous
//
#include <hip/hip_runtime.h>

// GridSamplePScan: out[b,t,c] = sum_{k<=t} bilinear(images[b,k,c], wrap(base + cum_t - cum_k))
// B=4, L=32, C=16, H=W=64, fp32 in/out.
//
// R12 = R9 (proven 71.6us) + forced v_fma_mix MAC + halved coords with the
// REFERENCE ASSOCIATION ORDER.
//   ERRATA (R3/R4/R5/R11 all failed with absmax == 1.3095703125 exactly):
//   those rounds computed fl((base+1) + rel); the reference computes
//   fl(fl(base + rel) + 1). The single-rounding difference flips floor()
//   cells -> O(1) errors. It was never a barrier race.
//   Correct halved form (bitwise-equal proof):
//     bxh = base_x*0.5, dh = (cum_t - cum_k)*0.5 with cum stored *0.5:
//     s1h = fl(bxh+dh) = fl(base+rel)/2   (exact-halving commutes w/ rounding)
//     ux  = fl(s1h+0.5) = fl(fl(base+rel)+1)/2 = R9's ux bitwise. QED.

constexpr int BN = 4, LN = 32, CN = 16, HWn = 4096;
constexpr int FRAME = CN * HWn;
constexpr int PW = 66, PCELLS = PW * PW;                       // 4356 cells
constexpr int CHUNK_B = PCELLS * 16;                           // 69696 B
constexpr size_t TIMG_BYTES = (size_t)BN * LN * 2 * CHUNK_B;   // ~17.8 MB
constexpr size_t CUM_BYTES  = (size_t)BN * LN * HWn * 2 * 4;   // 4 MB

// ---------------------------------------------------------------------------
// images fp32 [B,L,C,H,W] -> fp16 padded [B*L][chh(2)][66][66][8ch] 16B cells.
// Cell (y,x): interior (1..64)^2 = image px (y-1,x-1); border = zeros.
// ---------------------------------------------------------------------------
__global__ __launch_bounds__(1024) void prep_pad(
        const float* __restrict__ img, float4* __restrict__ timg) {
    const int f = blockIdx.x >> 1, g = blockIdx.x & 1;         // frame, chhalf
    const float* src = img + (size_t)f * FRAME + g * (8 * HWn);
    float4* dst = timg + (size_t)blockIdx.x * PCELLS;
    for (int q = threadIdx.x; q < PCELLS; q += 1024) {
        const int y = q / PW, x = q - y * PW;
        union { float4 f4; _Float16 h[8]; } cell;
        if (y >= 1 && y <= 64 && x >= 1 && x <= 64) {
            const int p = ((y - 1) << 6) + (x - 1);
#pragma unroll
            for (int c = 0; c < 8; ++c)
                cell.h[c] = (_Float16)src[c * HWn + p];        // coalesced
        } else {
            cell.f4 = make_float4(0.f, 0.f, 0.f, 0.f);         // zero pad
        }
        dst[q] = cell.f4;
    }
}

// ---------------------------------------------------------------------------
// cumsum(flows) * 0.5 (exact scaling of the ROUNDED cumsum) -> [B*L][4096]
// ---------------------------------------------------------------------------
__global__ __launch_bounds__(256) void prep_cum(
        const float* __restrict__ flows, float2* __restrict__ cum) {
    const int b = blockIdx.x >> 4;
    const int p = ((blockIdx.x & 15) << 8) + threadIdx.x;
    const float* fl = flows + (size_t)b * (LN * 2 * HWn) + p;
    float cx = 0.f, cy = 0.f;
    for (int l = 0; l < LN; ++l) {              // ascending == jnp.cumsum
        cx += fl[(2 * l) * HWn];
        cy += fl[(2 * l + 1) * HWn];
        cum[(size_t)(b * LN + l) * HWn + p] =
            make_float2(cx * 0.5f, cy * 0.5f);  // exact *0.5
    }
}

// ---------------------------------------------------------------------------
// Guaranteed v_fma_mix_f32: acc += (float)f16(lo/hi of g) * w  (f32 fma)
// (op_sel_hi[0]=1 -> src0 is f16; op_sel[0] picks hi/lo half)
// ---------------------------------------------------------------------------
__device__ __forceinline__ void mix_lo(float& acc, unsigned g, float w) {
    asm("v_fma_mix_f32 %0, %1, %2, %0 op_sel_hi:[1,0,0]"
        : "+v"(acc) : "v"(g), "v"(w));
}
__device__ __forceinline__ void mix_hi(float& acc, unsigned g, float w) {
    asm("v_fma_mix_f32 %0, %1, %2, %0 op_sel:[1,0,0] op_sel_hi:[1,0,0]"
        : "+v"(acc) : "v"(g), "v"(w));
}
__device__ __forceinline__ void mac8(float* __restrict__ acc, uint4 g, float w) {
    mix_lo(acc[0], g.x, w); mix_hi(acc[1], g.x, w);
    mix_lo(acc[2], g.y, w); mix_hi(acc[3], g.y, w);
    mix_lo(acc[4], g.z, w); mix_hi(acc[5], g.z, w);
    mix_lo(acc[6], g.w, w); mix_hi(acc[7], g.w, w);
}

// ---------------------------------------------------------------------------
// Bilinear from padded LDS frame. No masks: pad cells are zero.
// ux = (bxh + dh) + 0.5 : ref association, halved (proof at file top).
// fx = fract(ux) = mod(v,2)/2 exact; ixp = fx*64+0.5 = ref ix + 1 bitwise.
// ---------------------------------------------------------------------------
__device__ __forceinline__ void px_step(const uint4* __restrict__ fr,
                                        float2 ct, float2 ck,
                                        float bxh, float byh,
                                        float* __restrict__ acc) {
    const float ux = (bxh + (ct.x - ck.x)) + 0.5f;  // ref add order, halved
    const float uy = (byh + (ct.y - ck.y)) + 0.5f;
    const float fx = ux - floorf(ux);               // [0,1)
    const float fy = uy - floorf(uy);
    const float ixp = fmaf(fx, 64.0f, 0.5f);        // [0.5, 64.5)
    const float iyp = fmaf(fy, 64.0f, 0.5f);
    const float xf = floorf(ixp), yf = floorf(iyp);
    const int x0p = (int)xf, y0p = (int)yf;         // [0, 64]
    const float wx1 = ixp - xf, wy1 = iyp - yf;
    const float wx0 = 1.0f - wx1, wy0 = 1.0f - wy1;
    const float w00 = wx0 * wy0, w10 = wx1 * wy0;
    const float w01 = wx0 * wy1, w11 = wx1 * wy1;
    const int i00 = y0p * PW + x0p;
    const uint4 g00 = fr[i00];                      // ds_read_b128
    const uint4 g10 = fr[i00 + 1];
    const uint4 g01 = fr[i00 + PW];
    const uint4 g11 = fr[i00 + PW + 1];
    mac8(acc, g00, w00);                            // 32x v_fma_mix_f32
    mac8(acc, g10, w10);
    mac8(acc, g01, w01);
    mac8(acc, g11, w11);
}

// ---------------------------------------------------------------------------
// 256 blocks x 1024 thr (1/CU). Block = (b, pxhalf, pair, chh); thread: 2 px,
// 8 ch, 2 t-phases (triangle-paired: 33 uniform k-iters). R7/R9 schedule.
// ---------------------------------------------------------------------------
__global__ __launch_bounds__(1024, 4) void gsps_lds(
        const float2* __restrict__ cum,
        const char* __restrict__ timg,
        float* __restrict__ out) {
    extern __shared__ char smem[];              // 2 x 69696 B double buffer
    const int bid = blockIdx.x;                 // 256 blocks
    const int xs  = bid & 7;                    // XCD slot
    const int b   = xs >> 1;                    // batch pinned to XCD pair
    const int pxh = xs & 1;
    const int seq = bid >> 3;
    const int pair = seq & 15;
    const int chh  = seq >> 4;
    const int tid  = threadIdx.x;
    const int t1 = 31 - pair;                   // heavy phase t
    const int t2 = pair;                        // light phase t

    const int px0 = (pxh << 11) + tid;
    const int px1 = px0 + 1024;
    // bxh = base_x/2 = (w+0.5)*2^-6 - 0.5   (both terms exact, diff exact)
    const float bx0 = ((float)(px0 & 63) + 0.5f) * 0.015625f - 0.5f;
    const float by0 = ((float)(px0 >> 6) + 0.5f) * 0.015625f - 0.5f;
    const float bx1 = ((float)(px1 & 63) + 0.5f) * 0.015625f - 0.5f;
    const float by1 = ((float)(px1 >> 6) + 0.5f) * 0.015625f - 0.5f;

    const float2* cb = cum + (size_t)b * (LN * HWn);
    // chunk base for (b, k, chh): ((b*32 + k)*2 + chh) * CHUNK_B
    const size_t chunk0 = ((size_t)b * LN * 2 + chh) * CHUNK_B;
    const unsigned wbase = (unsigned)(tid & ~63) << 4;   // wave-uniform

    // LDS dest: wave-uniform base (+ HW lane*16); global src per-lane.
#define STAGE(KK, BUF) do {                                                   \
    const char* gsrc = timg + chunk0 + (size_t)(KK) * (2 * CHUNK_B);          \
    char* lbase = smem + (BUF) * CHUNK_B + wbase;                             \
    _Pragma("unroll")                                                         \
    for (int j = 0; j < 4; ++j) {                                             \
        __builtin_amdgcn_global_load_lds(                                     \
            (const __attribute__((address_space(1))) void*)                  \
                (gsrc + (j * 16384 + tid * 16)),                              \
            (__attribute__((address_space(3))) void*)(lbase + j * 16384),    \
            16, 0, 0);                                                        \
    }                                                                         \
    if (tid < PCELLS - 4096) {  /* tail cells 4096..4355 */                   \
        __builtin_amdgcn_global_load_lds(                                     \
            (const __attribute__((address_space(1))) void*)                  \
                (gsrc + (65536 + tid * 16)),                                  \
            (__attribute__((address_space(3))) void*)(lbase + 65536),        \
            16, 0, 0);                                                        \
    }                                                                         \
} while (0)

    float acc0[8] = {0}, acc1[8] = {0};
    float2 ct0 = make_float2(0.f, 0.f), ct1 = ct0;
    float2 ckp0 = cb[px0], ckp1 = cb[px1];      // ck prefetch for iter 0

    STAGE(0, 0);                                // prologue: frame 0 -> buf0

    for (int i = 0; i < 33; ++i) {
        const bool ph2 = (i > t1);
        const int k = ph2 ? (i - t1 - 1) : i;
        const int t = ph2 ? t2 : t1;

        // barrier drains vmcnt(0): STAGE(i) complete; buf^1 readers done
        __syncthreads();
        if (i < 32) {                           // issue next DMA now; it
            const int kn = (i + 1 > t1) ? (i - t1) : (i + 1);
            STAGE(kn, (i + 1) & 1);             // drains at NEXT barrier
        }

        const float2 ck0 = ckp0, ck1 = ckp1;
        if (i < 32) {                           // prefetch next ck pair
            const int kn = (i + 1 > t1) ? (i - t1) : (i + 1);
            ckp0 = cb[kn * HWn + px0];
            ckp1 = cb[kn * HWn + px1];
        }
        if (k == 0) {                           // phase start
            ct0 = cb[t * HWn + px0];
            ct1 = cb[t * HWn + px1];
#pragma unroll
            for (int c = 0; c < 8; ++c) { acc0[c] = 0.f; acc1[c] = 0.f; }
        }
        const uint4* fr = (const uint4*)(smem + (i & 1) * CHUNK_B);
        px_step(fr, ct0, ck0, bx0, by0, acc0);
        px_step(fr, ct1, ck1, bx1, by1, acc1);

        if (k == t) {                           // phase end: write out
            float* op = out + ((size_t)(b * LN + t) * CN + chh * 8) * HWn;
#pragma unroll
            for (int c = 0; c < 8; ++c) {
                op[c * HWn + px0] = acc0[c];
                op[c * HWn + px1] = acc1[c];
            }
        }
    }
#undef STAGE
}

// ---------------------------------------------------------------------------
// Fallback (ws too small / attr fails): direct fp32 gather (proven R1 kernel).
// ---------------------------------------------------------------------------
__global__ __launch_bounds__(256) void gsps_slow(
        const float* __restrict__ flows,
        const float* __restrict__ img,
        float* __restrict__ out) {
    const int bi = blockIdx.x;
    const int tile = bi & 15;
    const int rest = bi >> 4;
    const int t = 31 - (rest & 31);
    const int b = rest >> 5;
    const int p = (tile << 8) + threadIdx.x;
    const int h = p >> 6, w = p & 63;
    const float base_x = ((float)w + 0.5f) * 0.03125f - 1.0f;
    const float base_y = ((float)h + 0.5f) * 0.03125f - 1.0f;
    const float* fl = flows + (size_t)b * (LN * 2 * HWn) + p;

    float ctx = 0.f, cty = 0.f;
    for (int j = 0; j <= t; ++j) { ctx += fl[(2*j)*HWn]; cty += fl[(2*j+1)*HWn]; }

    float acc[16];
#pragma unroll
    for (int c = 0; c < 16; ++c) acc[c] = 0.f;

    float ckx = 0.f, cky = 0.f;
    for (int k = 0; k <= t; ++k) {
        ckx += fl[(2*k)*HWn]; cky += fl[(2*k+1)*HWn];
        float vx = (base_x + (ctx - ckx)) + 1.0f;
        float vy = (base_y + (cty - cky)) + 1.0f;
        float mx = vx - 2.0f * floorf(vx * 0.5f);
        float my = vy - 2.0f * floorf(vy * 0.5f);
        const float ix = ((mx - 1.0f) + 1.0f) * 32.0f - 0.5f;
        const float iy = ((my - 1.0f) + 1.0f) * 32.0f - 0.5f;
        const float x0f = floorf(ix), y0f = floorf(iy);
        const int x0 = (int)x0f, y0 = (int)y0f;
        const float wx1 = ix - x0f, wy1 = iy - y0f;
        const float wx0 = 1.0f - wx1, wy0 = 1.0f - wy1;
        const int x1 = x0 + 1, y1 = y0 + 1;
        const float fx0 = (x0 >= 0) ? 1.0f : 0.0f;
        const float fx1 = (x1 <= 63) ? 1.0f : 0.0f;
        const float fy0 = (y0 >= 0) ? 1.0f : 0.0f;
        const float fy1 = (y1 <= 63) ? 1.0f : 0.0f;
        const int x0c = (x0 < 0) ? 0 : x0, x1c = (x1 > 63) ? 63 : x1;
        const int y0c = (y0 < 0) ? 0 : y0, y1c = (y1 > 63) ? 63 : y1;
        const float w00 = (wx0*wy0)*(fx0*fy0), w10 = (wx1*wy0)*(fx1*fy0);
        const float w01 = (wx0*wy1)*(fx0*fy1), w11 = (wx1*wy1)*(fx1*fy1);
        const float* frm = img + (size_t)(b * LN + k) * FRAME;
        const int i00 = (y0c<<6)+x0c, i10 = (y0c<<6)+x1c;
        const int i01 = (y1c<<6)+x0c, i11 = (y1c<<6)+x1c;
#pragma unroll
        for (int c = 0; c < 16; ++c) {
            const float* pl = frm + c * HWn;
            acc[c] += ((w00*pl[i00] + w10*pl[i10]) + w01*pl[i01]) + w11*pl[i11];
        }
    }
    float* op = out + (size_t)(b * LN + t) * FRAME + p;
#pragma unroll
    for (int c = 0; c < 16; ++c) op[c * HWn] = acc[c];
}

extern "C" void kernel_launch(void* const* d_in, const int* in_sizes, int n_in,
                              void* d_out, int out_size, void* d_ws, size_t ws_size,
                              hipStream_t stream) {
    const float* flows  = (const float*)d_in[0];   // [4,32,2,64,64] f32
    const float* images = (const float*)d_in[1];   // [4,32,16,64,64] f32
    float* out = (float*)d_out;                    // [4,32,16,64,64] f32

    bool fast = (ws_size >= TIMG_BYTES + CUM_BYTES);
    if (fast) {
        hipError_t e = hipFuncSetAttribute(
            reinterpret_cast<const void*>(&gsps_lds),
            hipFuncAttributeMaxDynamicSharedMemorySize, 2 * CHUNK_B);
        if (e != hipSuccess) fast = false;
    }
    if (fast) {
        float4* timg = (float4*)d_ws;
        float2* cumw = (float2*)((char*)d_ws + TIMG_BYTES);
        prep_pad<<<BN * LN * 2, 1024, 0, stream>>>(images, timg);
        prep_cum<<<BN * 16, 256, 0, stream>>>(flows, cumw);
        gsps_lds<<<256, 1024, 2 * CHUNK_B, stream>>>(
            cumw, (const char*)timg, out);
    } else {
        gsps_slow<<<BN * LN * 16, 256, 0, stream>>>(flows, images, out);
    }
}